// Round 6
// baseline (34074.533 us; speedup 1.0000x reference)
//
#include <hip/hip_runtime.h>
#include <hip/hip_bf16.h>

#define N        2048
#define T_STEPS  8192
#define DIN      64
#define KW       256     // launched WGs; exactly ONE XCD group of 32 is elected
#define NTHR     512     // 8 waves
#define GSIZE    32      // WGs in the elected group
#define BLKROWS  64      // rows per WG (N / 32)
#define CAP      320     // padded nonzeros per row (mean 205, sigma 13.6)
#define NPL      40      // CAP / 8 nonzeros per lane (8-lane row groups)
#define SPIN_SW  4096    // sc0 spins before a wave permanently switches to sc1
#define SCOPE_AG __HIP_MEMORY_SCOPE_AGENT
#define SCOPE_WG __HIP_MEMORY_SCOPE_WORKGROUP

typedef unsigned long long u64;
typedef unsigned int v4u __attribute__((ext_vector_type(4)));

// ---------------------------------------------------------------------------
// INTRA-XCD scan with a SELF-RESCUING protocol (R4/R5 failed all-or-nothing).
//
// Invariant: every publish ends with a DEVICE-SCOPE store (the R0-proven
// instruction), so the device coherence point always holds the truth. The
// preceding plain workgroup-scope store is an opportunistic fast-local-L2
// update for same-XCD consumers. Consumers poll with sc0 (local L2). A wave
// that spins > SPIN_SW iterations (stale local line => group not actually
// coherent at L2) permanently switches to sc1 polls — the R0-proven
// device-coherent path. Therefore:
//   - intra-XCD coherence works  -> ~250cy polls, big win;
//   - XCC_ID lied / stores skip L2 -> one-time 4096-spin cost, then R0 speed;
// Either way the kernel PASSES; the bench tells us which world we're in.
//
// Election: all 256 WGs rank per-XCD (HW_REG_XCC_ID + atomics in d_ws),
// release/acquire rendezvous, then everyone deterministically picks the
// lowest XCD with >= GSIZE WGs; its ranks 0..31 run the scan (64 rows each),
// everyone else exits. Exchange atoms ex[t&1][k] = (fp32_bits<<32)|t with
// depth-2 flow control (unchanged, group-local). Exchange + counters live in
// d_ws ([0,32K) + [32K,32K+64) — R0's proven region; d_out untouched).
// ---------------------------------------------------------------------------

__global__ void init_kernel(u64* ws) {
    int i = threadIdx.x + blockIdx.x * blockDim.x;
    // zero ex[2][2048] (4096 u64) + 16 u32 counters (8 u64) right after
    if (i < 2 * N + 8) ws[i] = 0ull;
}

extern "C" __global__ void __launch_bounds__(NTHR, 1)
reservoir_scan(const float* __restrict__ W,
               const float* __restrict__ W_in,
               const float* __restrict__ u,
               const float* __restrict__ noise,
               u64* __restrict__ ex,                 // [2][N] in d_ws
               unsigned* __restrict__ cnt,           // [16] in d_ws + 32K
               __hip_bfloat16* __restrict__ states)  // [T][N]
{
    __shared__ u64   Wst[8][2][CAP];  // 40 KB — per-wave 2-row staging (init)
    __shared__ float s_s[2][N];       // 16 KB — double-buffered state
    __shared__ int   s_exit, s_go, s_rank;

    const int tid = threadIdx.x;
    const int wv  = tid >> 6;        // wave 0..7
    const int ln  = tid & 63;        // lane 0..63
    const int l8  = ln & 7;          // lane-in-group
    const int g   = ln >> 3;         // row group 0..7 within wave

    // --- rendezvous: per-XCD rank, then elect one complete group ---
    if (tid == 0) {
        unsigned xcd;
        asm volatile("s_getreg_b32 %0, hwreg(HW_REG_XCC_ID)" : "=s"(xcd));
        xcd &= 7u;
        unsigned r = __hip_atomic_fetch_add(&cnt[xcd], 1u, __ATOMIC_RELAXED, SCOPE_AG);
        __hip_atomic_fetch_add(&cnt[8], 1u, __ATOMIC_RELEASE, SCOPE_AG);
        unsigned tot; int guard = 0;
        do {
            tot = __hip_atomic_load(&cnt[8], __ATOMIC_ACQUIRE, SCOPE_AG);
        } while (tot < KW && ++guard < (1 << 18));
        int target = -1;
        for (int x = 0; x < 8; ++x) {
            unsigned c = __hip_atomic_load(&cnt[x], __ATOMIC_RELAXED, SCOPE_AG);
            if (target < 0 && c >= GSIZE) target = x;
        }
        s_go   = (tot >= KW) && ((int)xcd == target) && (r < GSIZE);
        s_rank = (int)r;
        s_exit = 0;
    }
    __syncthreads();
    if (!s_go) return;                       // non-elected WGs free their CUs
    const int r0   = s_rank * BLKROWS;       // this WG's 64-row block
    const int grow = r0 + wv * 8 + g;        // this 8-lane group's row

    // --- one-time sparse extraction: ballot-compact, 4 phases x 2 rows ---
    u64 wreg[NPL];
    for (int ph = 0; ph < 4; ++ph) {
        for (int r = 0; r < 2; ++r) {
            const size_t rowoff = (size_t)(r0 + wv * 8 + ph * 2 + r) * N;
            int base = 0;
            for (int ch = 0; ch < 32; ++ch) {
                int col = ch * 64 + ln;
                float w = W[rowoff + col];
                u64 m = __ballot(w != 0.0f);
                if (w != 0.0f) {
                    int pos = base + (int)__popcll(m & ((1ull << ln) - 1ull));
                    if (pos < CAP)
                        Wst[wv][r][pos] = ((u64)__float_as_uint(w) << 32) | (unsigned)col;
                }
                base += (int)__popcll(m);
            }
            for (int p = base + ln; p < CAP; p += 64)
                Wst[wv][r][p] = 0ull;   // val=0, col=0 — contributes nothing
        }
        __syncthreads();
        if ((g >> 1) == ph) {           // groups 2ph, 2ph+1 read their rows
            #pragma unroll
            for (int i = 0; i < NPL; ++i)
                wreg[i] = Wst[wv][g & 1][l8 + 8 * i];
        }
        __syncthreads();
    }

    // --- input-drive weights: win[j] = W_in[grow][l8 + 8j] ---
    float win[8];
    #pragma unroll
    for (int j = 0; j < 8; ++j)
        win[j] = W_in[(size_t)grow * DIN + l8 + 8 * j];

    bool slow = false;   // wave-uniform: permanent sc0 -> sc1 switch

    for (int t = 0; t < T_STEPS; ++t) {
        const int buf = t & 1;

        // independent loads issued early — overlap with the spin-gather
        float ul = u[t * DIN + ln];
        float nz = 0.0f;
        if (l8 == 0) nz = noise[(size_t)t * N + grow];

        u64* exb = ex + (size_t)buf * N;
        const u64* a0 = exb + 2 * tid;           // atoms 2tid, 2tid+1
        const u64* a1 = exb + 2 * tid + 1024;    // atoms +1024
        v4u q0, q1;
        const unsigned tu = (unsigned)t;
        bool good = false;
        int gd = 0;
        for (;;) {
            if (!slow) {
                // fast path: bypass L1, serve from the XCD's own L2
                asm volatile("global_load_dwordx4 %0, %1, off sc0" : "=v"(q0) : "v"(a0));
                asm volatile("global_load_dwordx4 %0, %1, off sc0" : "=v"(q1) : "v"(a1));
            } else {
                // proven device-coherent path (R0-R3)
                asm volatile("global_load_dwordx4 %0, %1, off sc1" : "=v"(q0) : "v"(a0));
                asm volatile("global_load_dwordx4 %0, %1, off sc1" : "=v"(q1) : "v"(a1));
            }
            asm volatile("s_waitcnt vmcnt(0)" ::: "memory");
            int ok = (q0.x == tu) + (q0.z == tu) + (q1.x == tu) + (q1.z == tu);
            int ov = (q0.x > tu) | (q0.z > tu) | (q1.x > tu) | (q1.z > tu);
            if (__all(ok == 4)) { good = true; break; }
            if (__any(ov) || ++gd > (1 << 17)) { s_exit = 1; break; }
            if (gd == SPIN_SW) slow = true;   // stale local L2: go coherent
        }
        if (good) {
            *(float2*)&s_s[buf][2 * tid] =
                make_float2(__uint_as_float(q0.y), __uint_as_float(q0.w));
            *(float2*)&s_s[buf][2 * tid + 1024] =
                make_float2(__uint_as_float(q1.y), __uint_as_float(q1.w));
        }

        __syncthreads();          // single barrier per step (s_s is dbuf'd)
        if (s_exit) return;       // genuine protocol break: loud failure

        // --- sparse matvec: 40 LDS gathers + 40 FMAs per lane ---
        float acc = 0.0f;
        #pragma unroll
        for (int i = 0; i < NPL; ++i) {
            unsigned col = (unsigned)wreg[i];
            float    w   = __uint_as_float((unsigned)(wreg[i] >> 32));
            acc += w * s_s[buf][col];
        }
        // input drive: Sum_j W_in[grow][l8+8j] * u[t][l8+8j] via shuffles
        #pragma unroll
        for (int j = 0; j < 8; ++j)
            acc += win[j] * __shfl(ul, l8 + 8 * j, 64);
        // reduce within the 8-lane group (all 8 rows of the wave at once)
        acc += __shfl_xor(acc, 1, 64);
        acc += __shfl_xor(acc, 2, 64);
        acc += __shfl_xor(acc, 4, 64);

        if (l8 == 0) {
            float pre = acc + 0.01f * nz;
            // fast tanh: sign * (1 - 2/(exp2(2*log2e*|x|)+1))
            float ax = __builtin_fabsf(pre);
            float e  = __builtin_amdgcn_exp2f(ax * 2.8853900817779268f);
            float th = 1.0f - 2.0f * __builtin_amdgcn_rcpf(e + 1.0f);
            th = __builtin_copysignf(th, pre);
            float snew = 0.7f * s_s[buf][grow] + 0.3f * th;
            u64 pk = ((u64)__float_as_uint(snew) << 32) | (unsigned)(t + 1);
            u64* dst = &ex[(size_t)(buf ^ 1) * N + grow];
            // 1) opportunistic fast local-L2 update (same-XCD consumers)
            __hip_atomic_store(dst, pk, __ATOMIC_RELAXED, SCOPE_WG);
            // 2) ground truth at the device coherence point (R0-proven)
            __hip_atomic_store(dst, pk, __ATOMIC_RELAXED, SCOPE_AG);
            states[(size_t)t * N + grow] = __float2bfloat16(snew);
        }
        // no trailing barrier: overwriting s_s[buf] at step t+2 requires the
        // group's t+1 tags, which data-depend on their reads of s_s[buf].
    }
}

// ---------------------------------------------------------------------------
// readout: out[t][d] = states[t] . w_out[d] + b_out[d].
// ---------------------------------------------------------------------------
__global__ void __launch_bounds__(256)
out_gemm(const __hip_bfloat16* __restrict__ states,
         const float* __restrict__ w_out,
         const float* __restrict__ b_out,
         float* __restrict__ out)
{
    __shared__ float s_lds[4][N];   // 32 KiB
    const int tid = threadIdx.x;
    const int wv  = tid >> 6, ln = tid & 63;
    const int t0  = blockIdx.x * 4;

    for (int idx = tid; idx < 4 * N; idx += 256) {
        int tt = idx >> 11, kk = idx & (N - 1);
        s_lds[tt][kk] = __bfloat162float(states[(size_t)(t0 + tt) * N + kk]);
    }
    __syncthreads();

    const int t = t0 + wv;
    const float4* s4 = (const float4*)&s_lds[wv][0];
    for (int d = 0; d < 64; ++d) {
        const float4* w4 = (const float4*)(w_out + (size_t)d * N);
        float a = 0.0f;
        #pragma unroll
        for (int j = 0; j < 8; ++j) {
            const int ci = ln + 64 * j;
            float4 wv4 = w4[ci];
            float4 sv  = s4[ci];
            a += wv4.x * sv.x + wv4.y * sv.y + wv4.z * sv.z + wv4.w * sv.w;
        }
        #pragma unroll
        for (int off = 1; off < 64; off <<= 1) a += __shfl_xor(a, off, 64);
        if (ln == 0) out[t * 64 + d] = a + b_out[d];
    }
}

// ---------------------------------------------------------------------------
extern "C" void kernel_launch(void* const* d_in, const int* in_sizes, int n_in,
                              void* d_out, int out_size, void* d_ws, size_t ws_size,
                              hipStream_t stream)
{
    const float* u     = (const float*)d_in[0];   // (T, DIN)
    const float* noise = (const float*)d_in[1];   // (T, N)
    const float* W_in  = (const float*)d_in[2];   // (N, DIN)
    const float* W     = (const float*)d_in[3];   // (N, N)
    const float* w_out = (const float*)d_in[4];   // (64, N)
    const float* b_out = (const float*)d_in[5];   // (64,)
    float* out = (float*)d_out;

    // workspace (R0-proven region): [0, 32K): ex[2][N] u64 |
    // [32K, 32K+64): rank counters u32[16] | [64K, 64K+32M): states bf16
    u64*      ex     = (u64*)d_ws;
    unsigned* cnt    = (unsigned*)((char*)d_ws + 32768);
    __hip_bfloat16* states = (__hip_bfloat16*)((char*)d_ws + 65536);

    hipLaunchKernelGGL(init_kernel, dim3((2 * N + 8 + 255) / 256), dim3(256),
                       0, stream, (u64*)d_ws);

    void* args[] = { (void*)&W, (void*)&W_in, (void*)&u, (void*)&noise,
                     (void*)&ex, (void*)&cnt, (void*)&states };
    hipLaunchCooperativeKernel((const void*)reservoir_scan,
                               dim3(KW), dim3(NTHR), args, 0, stream);

    hipLaunchKernelGGL(out_gemm, dim3(T_STEPS / 4), dim3(256), 0, stream,
                       states, w_out, b_out, out);
}

// Round 8
// 14712.244 us; speedup vs baseline: 2.3161x; 2.3161x over previous
//
#include <hip/hip_runtime.h>
#include <hip/hip_bf16.h>

#define N        2048
#define T_STEPS  8192
#define DIN      64
#define KW       128     // workgroups, 1 per CU
#define ROWS     16      // N / KW rows per WG
#define NTHR     256
#define CAP      320     // padded nonzeros per row (mean 205, sigma 13.6)
#define NNZL     20      // CAP / 16 nonzeros per lane (16-lane row groups)
#define SCOPE_AG __HIP_MEMORY_SCOPE_AGENT

typedef unsigned long long u64;
typedef unsigned int v4u __attribute__((ext_vector_type(4)));

// ---------------------------------------------------------------------------
// Exchange protocol: ex[t&1][k] holds s_t[k] as (fp32_bits<<32)|t — value and
// tag in one naturally-atomic 8-B atom. Producers: one relaxed agent-scope
// 64-bit store. Consumers: 16-B sc1 polls (each 8-B half self-validates via
// its tag; tearing harmless). Depth-2 flow control: a slot can only advance
// to tag t+2 after ALL WGs consumed tag t (race-free).
//
// R8 revision (single change vs the proven 12.2ms R0 kernel): the publish
// store is NON-TEMPORAL (`global_store_dwordx2 ... sc1 nt`). Counter
// forensics: WRITE_SIZE == exact exchange+states bytes and FETCH_SIZE excess
// == stored-atoms x 64B line => every publish write-ALLOCATES (RFO: fetch
// full line from memory, ~900cy) before writing back. The exchange lines
// ping-pong through the memory side, making both store-visibility and the
// consumer polls HBM-latency-class. `nt` skips the allocation (no RFO fetch,
// no dirty residency) while `sc1` keeps device-scope visibility. If the RFO
// theory is right, FETCH_SIZE collapses by ~64KB/step and the step's latency
// chain shortens; if neutral, the write path is off the critical chain.
// ---------------------------------------------------------------------------

__global__ void init_kernel(u64* ex0) {
    int i = threadIdx.x + blockIdx.x * blockDim.x;
    if (i < N) ex0[i] = 0ull;   // s_0 = 0.0f tagged 0; ex[1] keeps poison
                                // tags (0xAAAAAAAA matches no t in [0,8192]).
}

extern "C" __global__ void __launch_bounds__(NTHR, 1)
reservoir_scan(const float* __restrict__ W,
               const float* __restrict__ W_in,
               const float* __restrict__ u,
               const float* __restrict__ noise,
               u64* __restrict__ ex,                 // [2][N] value+tag atoms
               __hip_bfloat16* __restrict__ states)  // [T][N]
{
    __shared__ u64   Wp[ROWS][CAP];   // 40 KB — sparse staging (init only)
    __shared__ float s_s[2][N];       // 16 KB — double-buffered state
    __shared__ int   s_timeout;

    const int tid = threadIdx.x;
    const int wg  = blockIdx.x;
    const int wv  = tid >> 6;        // wave 0..3
    const int ln  = tid & 63;        // lane 0..63
    const int r0  = wg * ROWS;       // first global row of this WG
    const int l   = ln & 15;         // lane-in-group
    const int g   = ln >> 4;         // row group 0..3
    const int lr  = wv * 4 + g;      // local row this group owns
    const int grow = r0 + lr;        // its global row

    // --- one-time sparse extraction: ballot-compact this wave's 4 rows ---
    for (int r = 0; r < 4; ++r) {
        const int xlr = wv * 4 + r;
        const size_t rowoff = (size_t)(r0 + xlr) * N;
        int base = 0;
        for (int ch = 0; ch < 32; ++ch) {
            int col = ch * 64 + ln;
            float w = W[rowoff + col];
            u64 m = __ballot(w != 0.0f);
            if (w != 0.0f) {
                int pos = base + (int)__popcll(m & ((1ull << ln) - 1ull));
                if (pos < CAP)
                    Wp[xlr][pos] = ((u64)__float_as_uint(w) << 32) | (unsigned)col;
            }
            base += (int)__popcll(m);
        }
        for (int p = base + ln; p < CAP; p += 64)
            Wp[xlr][p] = 0ull;        // val=0, col=0 — contributes nothing
    }
    if (tid == 0) s_timeout = 0;
    __syncthreads();

    // --- sparse slice to registers: lane (g,l) takes row lr's slots l+16i ---
    u64 wreg[NNZL];
    #pragma unroll
    for (int i = 0; i < NNZL; ++i)
        wreg[i] = Wp[lr][l + 16 * i];

    // --- input-drive weights: win[j] = W_in[grow][l + 16j] ---
    float win[4];
    #pragma unroll
    for (int j = 0; j < 4; ++j)
        win[j] = W_in[(size_t)grow * DIN + l + 16 * j];
    __syncthreads();   // Wp dead from here

    // this thread's 4 atom-pairs for polling: p_i = wv*256 + 64i + ln
    const int p0 = wv * 256 + ln;
    bool use_b128 = true;

    for (int t = 0; t < T_STEPS; ++t) {
        const int buf = t & 1;

        // independent loads issued early — overlap with the spin-gather
        float ul = u[t * DIN + ln];
        float nz = 0.0f;
        if (l == 0) nz = noise[(size_t)t * N + grow];

        u64* exb = ex + (size_t)buf * N;
        bool got = false;

        if (use_b128) {
            const u64* a0 = exb + 2 * (p0);
            const u64* a1 = exb + 2 * (p0 + 64);
            const u64* a2 = exb + 2 * (p0 + 128);
            const u64* a3 = exb + 2 * (p0 + 192);
            v4u q0, q1, q2, q3;
            int gd = 0;
            for (;;) {
                asm volatile("global_load_dwordx4 %0, %1, off sc1" : "=v"(q0) : "v"(a0));
                asm volatile("global_load_dwordx4 %0, %1, off sc1" : "=v"(q1) : "v"(a1));
                asm volatile("global_load_dwordx4 %0, %1, off sc1" : "=v"(q2) : "v"(a2));
                asm volatile("global_load_dwordx4 %0, %1, off sc1" : "=v"(q3) : "v"(a3));
                asm volatile("s_waitcnt vmcnt(0)" ::: "memory");
                int ok = (q0.x == (unsigned)t) + (q0.z == (unsigned)t)
                       + (q1.x == (unsigned)t) + (q1.z == (unsigned)t)
                       + (q2.x == (unsigned)t) + (q2.z == (unsigned)t)
                       + (q3.x == (unsigned)t) + (q3.z == (unsigned)t);
                if (__all(ok == 8)) { got = true; break; }
                if (++gd > 2048) { use_b128 = false; break; }  // sc1 hedge
            }
            if (got) {
                *(float2*)&s_s[buf][2 * (p0      )] = make_float2(__uint_as_float(q0.y), __uint_as_float(q0.w));
                *(float2*)&s_s[buf][2 * (p0 +  64)] = make_float2(__uint_as_float(q1.y), __uint_as_float(q1.w));
                *(float2*)&s_s[buf][2 * (p0 + 128)] = make_float2(__uint_as_float(q2.y), __uint_as_float(q2.w));
                *(float2*)&s_s[buf][2 * (p0 + 192)] = make_float2(__uint_as_float(q3.y), __uint_as_float(q3.w));
            }
        }
        if (!got) {
            // proven per-atom fallback (also permanent if sc1 ever misbehaves)
            unsigned pend = 0xFFu;
            int guard = 0;
            while (pend) {
                #pragma unroll
                for (int h = 0; h < 8; ++h) {
                    if (pend & (1u << h)) {
                        int atom = 2 * (p0 + 64 * (h >> 1)) + (h & 1);
                        u64 v = __hip_atomic_load(&exb[atom], __ATOMIC_RELAXED, SCOPE_AG);
                        if ((unsigned)v == (unsigned)t) {
                            s_s[buf][atom] = __uint_as_float((unsigned)(v >> 32));
                            pend &= ~(1u << h);
                        }
                    }
                }
                if (++guard > (1 << 17)) { s_timeout = 1; break; }
            }
        }

        __syncthreads();          // single barrier per step (s_s is dbuf'd)
        if (s_timeout) return;    // uniform abort instead of an eternal hang

        // --- sparse matvec: 20 LDS gathers + 20 FMAs per lane ---
        float acc = 0.0f;
        #pragma unroll
        for (int i = 0; i < NNZL; ++i) {
            unsigned col = (unsigned)wreg[i];
            float    w   = __uint_as_float((unsigned)(wreg[i] >> 32));
            acc += w * s_s[buf][col];
        }
        // input drive: Sum_j W_in[grow][l+16j] * u[t][l+16j] via shuffles
        #pragma unroll
        for (int j = 0; j < 4; ++j)
            acc += win[j] * __shfl(ul, l + 16 * j, 64);
        // reduce within the 16-lane group (all 4 rows of the wave at once)
        #pragma unroll
        for (int off = 1; off < 16; off <<= 1)
            acc += __shfl_xor(acc, off, 64);

        if (l == 0) {
            float pre = acc + 0.01f * nz;
            // fast tanh: sign * (1 - 2/(exp2(2*log2e*|x|)+1))
            float ax = __builtin_fabsf(pre);
            float e  = __builtin_amdgcn_exp2f(ax * 2.8853900817779268f);
            float th = 1.0f - 2.0f * __builtin_amdgcn_rcpf(e + 1.0f);
            th = __builtin_copysignf(th, pre);
            float snew = 0.7f * s_s[buf][grow] + 0.3f * th;
            u64 pk = ((u64)__float_as_uint(snew) << 32) | (unsigned)(t + 1);
            // NON-TEMPORAL device-coherent publish: no write-allocate/RFO,
            // no dirty-line residency; sc1 keeps device-scope visibility.
            u64* dst = &ex[(size_t)(buf ^ 1) * N + grow];
            asm volatile("global_store_dwordx2 %0, %1, off sc1 nt"
                         :: "v"(dst), "v"(pk) : "memory");
            states[(size_t)t * N + grow] = __float2bfloat16(snew);
        }
        // no trailing barrier: overwriting s_s[buf] at step t+2 requires all
        // WGs' t+1 tags, which data-depend on their reads of s_s[buf].
    }
}

// ---------------------------------------------------------------------------
// readout: out[t][d] = states[t] . w_out[d] + b_out[d].
// ---------------------------------------------------------------------------
__global__ void __launch_bounds__(256)
out_gemm(const __hip_bfloat16* __restrict__ states,
         const float* __restrict__ w_out,
         const float* __restrict__ b_out,
         float* __restrict__ out)
{
    __shared__ float s_lds[4][N];   // 32 KiB
    const int tid = threadIdx.x;
    const int wv  = tid >> 6, ln = tid & 63;
    const int t0  = blockIdx.x * 4;

    for (int idx = tid; idx < 4 * N; idx += 256) {
        int tt = idx >> 11, kk = idx & (N - 1);
        s_lds[tt][kk] = __bfloat162float(states[(size_t)(t0 + tt) * N + kk]);
    }
    __syncthreads();

    const int t = t0 + wv;
    const float4* s4 = (const float4*)&s_lds[wv][0];
    for (int d = 0; d < 64; ++d) {
        const float4* w4 = (const float4*)(w_out + (size_t)d * N);
        float a = 0.0f;
        #pragma unroll
        for (int j = 0; j < 8; ++j) {
            const int ci = ln + 64 * j;
            float4 wv4 = w4[ci];
            float4 sv  = s4[ci];
            a += wv4.x * sv.x + wv4.y * sv.y + wv4.z * sv.z + wv4.w * sv.w;
        }
        #pragma unroll
        for (int off = 1; off < 64; off <<= 1) a += __shfl_xor(a, off, 64);
        if (ln == 0) out[t * 64 + d] = a + b_out[d];
    }
}

// ---------------------------------------------------------------------------
extern "C" void kernel_launch(void* const* d_in, const int* in_sizes, int n_in,
                              void* d_out, int out_size, void* d_ws, size_t ws_size,
                              hipStream_t stream)
{
    const float* u     = (const float*)d_in[0];   // (T, DIN)
    const float* noise = (const float*)d_in[1];   // (T, N)
    const float* W_in  = (const float*)d_in[2];   // (N, DIN)
    const float* W     = (const float*)d_in[3];   // (N, N)
    const float* w_out = (const float*)d_in[4];   // (64, N)
    const float* b_out = (const float*)d_in[5];   // (64,)
    float* out = (float*)d_out;

    // workspace: [0, 32K): ex[2][N] u64 | [64K, 64K+32M): states bf16
    u64* ex                = (u64*)d_ws;
    __hip_bfloat16* states = (__hip_bfloat16*)((char*)d_ws + 65536);

    hipLaunchKernelGGL(init_kernel, dim3((N + 255) / 256), dim3(256), 0, stream,
                       ex);

    void* args[] = { (void*)&W, (void*)&W_in, (void*)&u, (void*)&noise,
                     (void*)&ex, (void*)&states };
    hipLaunchCooperativeKernel((const void*)reservoir_scan,
                               dim3(KW), dim3(NTHR), args, 0, stream);

    hipLaunchKernelGGL(out_gemm, dim3(T_STEPS / 4), dim3(256), 0, stream,
                       states, w_out, b_out, out);
}